// Round 7
// baseline (584.062 us; speedup 1.0000x reference)
//
#include <hip/hip_runtime.h>
#include <hip/hip_bf16.h>

typedef __attribute__((ext_vector_type(8))) short short8;
typedef __attribute__((ext_vector_type(4))) short svec4;
typedef __attribute__((ext_vector_type(8))) __bf16 bf16x8;
typedef __attribute__((ext_vector_type(4))) float f32x4;

#define NN 100000
#define HD 384
#define K1T 22   // GEMM1 k-tiles (704/32; 700 padded)
#define K2T 24   // GEMM2 k-tiles ([h1 | he])
#define NBLK 98
#define PAN 16384   // bytes per A k-panel buffer [64][256B]

// d_ws byte offsets (unchanged layout)
#define OFF_B1  0
#define OFF_B2  540672
#define OFF_T   1130496
#define OFF_V   1139712
#define OFF_BI  1141248
#define OFF_IDX 1142784
#define OFF_CNT 1942784
#define OFF_OFFS 1943568
#define OFF_TOT 1944352

union Frag { short s[8]; bf16x8 v; };

__device__ __forceinline__ short f2bf(float f) {
  union { __bf16 h; short s; } u;
  u.h = (__bf16)f;
  return u.s;
}

__device__ __forceinline__ float elu(float v) {
  return v > 0.f ? v : __expf(v) - 1.f;
}

__global__ void prep_kernel(const float* __restrict__ W1g, const float* __restrict__ b1g,
                            const float* __restrict__ W2g, const float* __restrict__ b2g,
                            const float* __restrict__ W1e, const float* __restrict__ b1e,
                            const float* __restrict__ W2e, const float* __restrict__ b2e,
                            char* __restrict__ ws) {
  int t = blockIdx.x * 256 + threadIdx.x;
  short* B1 = (short*)(ws + OFF_B1);
  short* B2 = (short*)(ws + OFF_B2);
  float* Tt = (float*)(ws + OFF_T);
  float* Vt = (float*)(ws + OFF_V);
  float* Bi = (float*)(ws + OFF_BI);
  if (t < 33792) {                       // B1: (nt,kt,lane) -> 8 shorts
    int lane = t & 63, rest = t >> 6;
    int kt = rest % K1T, nt = rest / K1T;
    int col = nt * 16 + (lane & 15);
    int kb = kt * 32 + (lane >> 4) * 8;
    short8 v;
#pragma unroll
    for (int i = 0; i < 8; ++i) {
      int k = kb + i;
      v[i] = (k < 700) ? f2bf(W1g[k * 384 + col]) : (short)0;
    }
    *(short8*)(B1 + (size_t)t * 8) = v;
  } else if (t < 70656) {                // B2
    int t2 = t - 33792;
    int lane = t2 & 63, rest = t2 >> 6;
    int kt = rest % K2T, nt = rest / K2T;
    int col = nt * 16 + (lane & 15);
    int kb = kt * 32 + (lane >> 4) * 8;
    short8 v;
#pragma unroll
    for (int i = 0; i < 8; ++i) {
      int k = kb + i;
      v[i] = (k < 384) ? f2bf(W2g[k * 384 + col]) : f2bf(W2e[(k - 384) * 384 + col]);
    }
    *(short8*)(B2 + (size_t)t2 * 8) = v;
  } else if (t < 73728) {                // tables
    int r = t - 70656;
    int which = r / 384, c = r % 384;
    if (which < 6)       Tt[r] = W1e[which * 384 + c] + b1e[c];
    else if (which == 6) Vt[c] = W1e[6 * 384 + c];
    else                 Bi[c] = b2g[c] + b2e[c];
  }
}

__global__ void count_kernel(const float* __restrict__ isf1, const float* __restrict__ isf2,
                             char* __restrict__ ws) {
  int g = blockIdx.y;
  const float* isf = g ? isf2 : isf1;
  int i = blockIdx.x * 1024 + threadIdx.x;
  bool face = (i < NN) && (isf[i] > 0.5f);
  unsigned long long b = __ballot(face);
  __shared__ int wc[16];
  int lane = threadIdx.x & 63, wid = threadIdx.x >> 6;
  if (lane == 0) wc[wid] = __popcll(b);
  __syncthreads();
  if (threadIdx.x == 0) {
    int s = 0;
#pragma unroll
    for (int w = 0; w < 16; ++w) s += wc[w];
    ((int*)(ws + OFF_CNT))[g * NBLK + blockIdx.x] = s;
  }
}

__global__ void scan_kernel(char* __restrict__ ws) {
  int t = threadIdx.x;
  if (t < 2) {
    const int* cnt = (const int*)(ws + OFF_CNT) + t * NBLK;
    int* offs = (int*)(ws + OFF_OFFS) + t * NBLK;
    int* tot = (int*)(ws + OFF_TOT);
    int run = 0;
    for (int b = 0; b < NBLK; ++b) { offs[b] = run; run += cnt[b]; }
    tot[t] = run;
  }
}

__global__ void compact_kernel(const float* __restrict__ isf1, const float* __restrict__ isf2,
                               char* __restrict__ ws) {
  int g = blockIdx.y;
  const float* isf = g ? isf2 : isf1;
  const int* offs = (const int*)(ws + OFF_OFFS) + g * NBLK;
  int totF = ((const int*)(ws + OFF_TOT))[g];
  int* idx = (int*)(ws + OFF_IDX) + g * NN;
  int bx = blockIdx.x;
  int i = bx * 1024 + threadIdx.x;
  bool valid = i < NN;
  bool face = valid && (isf[i] > 0.5f);
  unsigned long long bf = __ballot(face);
  unsigned long long bv = __ballot(valid);
  int lane = threadIdx.x & 63, wid = threadIdx.x >> 6;
  __shared__ int wF[16], wV[16];
  if (lane == 0) { wF[wid] = __popcll(bf); wV[wid] = __popcll(bv); }
  __syncthreads();
  int baseF = 0, baseV = 0;
  for (int w = 0; w < wid; ++w) { baseF += wF[w]; baseV += wV[w]; }
  unsigned long long lmask = (1ull << lane) - 1ull;
  int pF = __popcll(bf & lmask);
  int pV = __popcll(bv & lmask);
  if (face) {
    idx[offs[bx] + baseF + pF] = i;
  } else if (valid) {
    int nfBefore = bx * 1024 - offs[bx];
    int nfIn = (baseV + pV) - (baseF + pF);
    idx[totF + nfBefore + nfIn] = i;
  }
}

// 64 gathered face rows/block, 256 thr = 4 waves, N-split-4: wave = 64r x 96c,
// acc f32x4[4][6]. A staged as double-buffered 128-col k-panels (2x16KB) with
// stage(p+1) || compute(p); 64-col tail. h1 [64][768B] (48KB) reuses the panel
// space; he overwrites h1 after GEMM2a. 3 blocks/CU. Line-aligned epilogue.
__global__ __launch_bounds__(256, 3) void face_embed_kernel(
    const float* __restrict__ x1, const int* __restrict__ et1, const float* __restrict__ ar1,
    const float* __restrict__ x2, const int* __restrict__ et2, const float* __restrict__ ar2,
    const float* __restrict__ b1g, const char* __restrict__ ws,
    float* __restrict__ out) {
  const int g = blockIdx.y;
  const float* x = g ? x2 : x1;
  const int* et  = g ? et2 : et1;
  const float* ar = g ? ar2 : ar1;
  float* o = out + (size_t)g * NN * HD;
  const int* idx = (const int*)(ws + OFF_IDX) + g * NN;
  const int totF = ((const int*)(ws + OFF_TOT))[g];
  const int nFB = (totF + 63) >> 6;
  const int bx = blockIdx.x;
  const int tid = threadIdx.x;

  if (bx >= nFB) {                       // ---- zero path (64 non-face rows/block) ----
    int totN = NN - totF;
    int base = (bx - nFB) * 64;
    if (base >= totN) return;
    const int* idxN = idx + totF;
    f32x4 z = {0.f, 0.f, 0.f, 0.f};
#pragma unroll
    for (int it = 0; it < 24; ++it) {
      int c = tid + it * 256;            // 64 rows x 96 f32x4 chunks = 6144
      int r = c / 96, cc = c % 96;
      if (base + r < totN) {
        int node = idxN[base + r];
        *(f32x4*)(o + (size_t)node * HD + cc * 4) = z;
      }
    }
    return;
  }

  // ---- GEMM path ----
  __shared__ char buf[49152];            // panels [0,16K)+[16K,32K); h1/he [0,48K)
  __shared__ int sN[64];

  const bf16x8* B1 = (const bf16x8*)(ws + OFF_B1);
  const bf16x8* B2 = (const bf16x8*)(ws + OFF_B2);
  const float* Tg  = (const float*)(ws + OFF_T);
  const float* Vg  = (const float*)(ws + OFF_V);
  const float* Big = (const float*)(ws + OFF_BI);

  const int row0 = bx * 64;
  if (tid < 64) sN[tid] = (row0 + tid < totF) ? idx[row0 + tid] : -1;
  __syncthreads();

  const int wid = tid >> 6, lane = tid & 63;
  const int lr = lane & 15, gq = lane >> 4;

  float b1c[6], b2c[6];
#pragma unroll
  for (int n = 0; n < 6; ++n) {
    int col = (wid * 6 + n) * 16 + lr;
    b1c[n] = b1g[col];
    b2c[n] = Big[col];
  }

  // ---- staging helpers (as lambdas over block state) ----
  auto stage_panel = [&](int p, char* base) {     // 128 cols: [64][256B], 2048 chunks
#pragma unroll
    for (int it = 0; it < 8; ++it) {
      int c = tid + it * 256;
      int r = c >> 5, cc = c & 31;
      int node = sN[r];
      if (node >= 0) {
        f32x4 v = *(const f32x4*)(x + (size_t)node * 700 + p * 128 + cc * 4);
        svec4 pk;
#pragma unroll
        for (int i = 0; i < 4; ++i) pk[i] = f2bf(v[i]);
        int byte = (r * 256 + cc * 8) ^ ((r & 7) << 4);
        *(svec4*)(base + byte) = pk;
      }
    }
  };
  auto stage_tail = [&](char* base) {             // 64 cols: [64][128B], 1024 chunks
#pragma unroll
    for (int it = 0; it < 4; ++it) {
      int c = tid + it * 256;
      int r = c >> 4, cc = c & 15;
      int node = sN[r];
      int byte = (r * 128 + cc * 8) ^ ((r & 7) << 4);
      if (cc == 15) {                             // k 700..703 -> zero
        *(unsigned long long*)(base + byte) = 0ull;
      } else if (node >= 0) {
        f32x4 v = *(const f32x4*)(x + (size_t)node * 700 + 640 + cc * 4);
        svec4 pk;
#pragma unroll
        for (int i = 0; i < 4; ++i) pk[i] = f2bf(v[i]);
        *(svec4*)(base + byte) = pk;
      }
    }
  };

  f32x4 acc[4][6] = {};

  // ======== GEMM1: double-buffered k-panels ========
  stage_panel(0, buf);
  __syncthreads();
#pragma unroll
  for (int p = 0; p < 5; ++p) {
    if (p < 4) stage_panel(p + 1, buf + ((p + 1) & 1) * PAN);
    else       stage_tail(buf + PAN);
    char* cur = buf + (p & 1) * PAN;
#pragma unroll
    for (int ktL = 0; ktL < 4; ++ktL) {
      Frag a[4];
#pragma unroll
      for (int mf = 0; mf < 4; ++mf) {
        int row = mf * 16 + lr;
        int byte = (row * 256 + ktL * 64 + gq * 16) ^ ((row & 7) << 4);
        a[mf].v = *(const bf16x8*)(cur + byte);
      }
#pragma unroll
      for (int n = 0; n < 6; ++n) {
        bf16x8 b = B1[((wid * 6 + n) * K1T + p * 4 + ktL) * 64 + lane];
#pragma unroll
        for (int mf = 0; mf < 4; ++mf)
          acc[mf][n] = __builtin_amdgcn_mfma_f32_16x16x32_bf16(a[mf].v, b, acc[mf][n], 0, 0, 0);
      }
    }
    __syncthreads();
  }
  {                                               // tail: kt 20,21 from buf1
    char* cur = buf + PAN;
#pragma unroll
    for (int ktL = 0; ktL < 2; ++ktL) {
      Frag a[4];
#pragma unroll
      for (int mf = 0; mf < 4; ++mf) {
        int row = mf * 16 + lr;
        int byte = (row * 128 + ktL * 64 + gq * 16) ^ ((row & 7) << 4);
        a[mf].v = *(const bf16x8*)(cur + byte);
      }
#pragma unroll
      for (int n = 0; n < 6; ++n) {
        bf16x8 b = B1[((wid * 6 + n) * K1T + 20 + ktL) * 64 + lane];
#pragma unroll
        for (int mf = 0; mf < 4; ++mf)
          acc[mf][n] = __builtin_amdgcn_mfma_f32_16x16x32_bf16(a[mf].v, b, acc[mf][n], 0, 0, 0);
      }
    }
  }
  __syncthreads();                                // tail reads done; buf free for h1

  // ======== h1 = elu(acc + b1) -> LDS [64][768B] swizzled ========
#pragma unroll
  for (int mf = 0; mf < 4; ++mf)
#pragma unroll
    for (int n = 0; n < 6; ++n) {
      int col = (wid * 6 + n) * 16 + lr;
#pragma unroll
      for (int r2 = 0; r2 < 4; ++r2) {
        int row = mf * 16 + 4 * gq + r2;
        float hv = elu(acc[mf][n][r2] + b1c[n]);
        int byte = (row * 768 + col * 2) ^ ((row & 15) << 4);
        *(short*)(buf + byte) = f2bf(hv);
      }
    }
  __syncthreads();

  // ======== GEMM2a: h1 @ W2g (kt 0..11) ========
  f32x4 acc2[4][6] = {};
#pragma unroll
  for (int kt = 0; kt < 12; ++kt) {
    Frag a[4];
#pragma unroll
    for (int mf = 0; mf < 4; ++mf) {
      int row = mf * 16 + lr;
      int byte = (row * 768 + (kt * 32 + gq * 8) * 2) ^ ((row & 15) << 4);
      a[mf].v = *(const bf16x8*)(buf + byte);
    }
#pragma unroll
    for (int n = 0; n < 6; ++n) {
      bf16x8 b = B2[((wid * 6 + n) * K2T + kt) * 64 + lane];
#pragma unroll
      for (int mf = 0; mf < 4; ++mf)
        acc2[mf][n] = __builtin_amdgcn_mfma_f32_16x16x32_bf16(a[mf].v, b, acc2[mf][n], 0, 0, 0);
    }
  }
  __syncthreads();

  // ======== he -> LDS (overwrite h1; conflict-free: banks = lane&31) ========
  {
    int hl = lane >> 5;                  // 0/1: row within pair
    int hc = (lane & 31) * 2;            // col-pair base
#pragma unroll
    for (int rr = 0; rr < 8; ++rr) {
      int row = wid * 16 + rr * 2 + hl;
      int node = sN[row];
      int e = 0; float a = 0.f;
      if (node >= 0) { e = et[node]; a = ar[node]; }
      const float* Tp = Tg + e * 384;
#pragma unroll
      for (int jj = 0; jj < 6; ++jj) {
        int c = hc + jj * 64;
        unsigned lo = (unsigned short)f2bf(elu(Tp[c]     + a * Vg[c]));
        unsigned hi = (unsigned short)f2bf(elu(Tp[c + 1] + a * Vg[c + 1]));
        int byte = (row * 768 + c * 2) ^ ((row & 15) << 4);
        *(unsigned*)(buf + byte) = lo | (hi << 16);
      }
    }
  }
  __syncthreads();

  // ======== GEMM2b: he @ W2e (kt 12..23) ========
#pragma unroll
  for (int kt = 0; kt < 12; ++kt) {
    Frag a[4];
#pragma unroll
    for (int mf = 0; mf < 4; ++mf) {
      int row = mf * 16 + lr;
      int byte = (row * 768 + (kt * 32 + gq * 8) * 2) ^ ((row & 15) << 4);
      a[mf].v = *(const bf16x8*)(buf + byte);
    }
#pragma unroll
    for (int n = 0; n < 6; ++n) {
      bf16x8 b = B2[((wid * 6 + n) * K2T + 12 + kt) * 64 + lane];
#pragma unroll
      for (int mf = 0; mf < 4; ++mf)
        acc2[mf][n] = __builtin_amdgcn_mfma_f32_16x16x32_bf16(a[mf].v, b, acc2[mf][n], 0, 0, 0);
    }
  }

  // ======== epilogue: +bias2, scatter store (wave region 384B line-aligned) ========
#pragma unroll
  for (int mf = 0; mf < 4; ++mf) {
#pragma unroll
    for (int r2 = 0; r2 < 4; ++r2) {
      int node = sN[mf * 16 + 4 * gq + r2];
      if (node >= 0) {
#pragma unroll
        for (int n = 0; n < 6; ++n) {
          int col = (wid * 6 + n) * 16 + lr;
          o[(size_t)node * HD + col] = acc2[mf][n][r2] + b2c[n];
        }
      }
    }
  }
}

extern "C" void kernel_launch(void* const* d_in, const int* in_sizes, int n_in,
                              void* d_out, int out_size, void* d_ws, size_t ws_size,
                              hipStream_t stream) {
  (void)n_in; (void)out_size; (void)ws_size; (void)in_sizes;
  const float* x1  = (const float*)d_in[0];
  const float* is1 = (const float*)d_in[1];
  const int*   et1 = (const int*)d_in[2];
  const float* ar1 = (const float*)d_in[3];
  const float* x2  = (const float*)d_in[4];
  const float* is2 = (const float*)d_in[5];
  const int*   et2 = (const int*)d_in[6];
  const float* ar2 = (const float*)d_in[7];
  const float* W1g = (const float*)d_in[8];
  const float* b1g = (const float*)d_in[9];
  const float* W2g = (const float*)d_in[10];
  const float* b2g = (const float*)d_in[11];
  const float* W1e = (const float*)d_in[12];
  const float* b1e = (const float*)d_in[13];
  const float* W2e = (const float*)d_in[14];
  const float* b2e = (const float*)d_in[15];
  float* out = (float*)d_out;
  char* ws = (char*)d_ws;

  prep_kernel<<<dim3(288), dim3(256), 0, stream>>>(W1g, b1g, W2g, b2g, W1e, b1e, W2e, b2e, ws);
  count_kernel<<<dim3(NBLK, 2), dim3(1024), 0, stream>>>(is1, is2, ws);
  scan_kernel<<<dim3(1), dim3(64), 0, stream>>>(ws);
  compact_kernel<<<dim3(NBLK, 2), dim3(1024), 0, stream>>>(is1, is2, ws);

  dim3 grid(NN / 64 + 2, 2);
  face_embed_kernel<<<grid, dim3(256), 0, stream>>>(
      x1, et1, ar1, x2, et2, ar2, b1g, ws, out);
}

// Round 8
// 470.930 us; speedup vs baseline: 1.2402x; 1.2402x over previous
//
#include <hip/hip_runtime.h>
#include <hip/hip_bf16.h>

typedef __attribute__((ext_vector_type(8))) short short8;
typedef __attribute__((ext_vector_type(4))) short svec4;
typedef __attribute__((ext_vector_type(8))) __bf16 bf16x8;
typedef __attribute__((ext_vector_type(4))) float f32x4;

#define NN 100000
#define HD 384
#define K1T 22   // GEMM1 k-tiles (704/32; 700 padded)
#define K2T 24   // GEMM2 k-tiles ([h1 | he])
#define NBLK 98

// d_ws byte offsets (unchanged layout)
#define OFF_B1  0
#define OFF_B2  540672
#define OFF_T   1130496
#define OFF_V   1139712
#define OFF_BI  1141248
#define OFF_IDX 1142784
#define OFF_CNT 1942784
#define OFF_OFFS 1943568
#define OFF_TOT 1944352

union Frag { short s[8]; bf16x8 v; };

__device__ __forceinline__ short f2bf(float f) {
  union { __bf16 h; short s; } u;
  u.h = (__bf16)f;
  return u.s;
}

__device__ __forceinline__ float elu(float v) {
  return v > 0.f ? v : __expf(v) - 1.f;
}

__global__ void prep_kernel(const float* __restrict__ W1g, const float* __restrict__ b1g,
                            const float* __restrict__ W2g, const float* __restrict__ b2g,
                            const float* __restrict__ W1e, const float* __restrict__ b1e,
                            const float* __restrict__ W2e, const float* __restrict__ b2e,
                            char* __restrict__ ws) {
  int t = blockIdx.x * 256 + threadIdx.x;
  short* B1 = (short*)(ws + OFF_B1);
  short* B2 = (short*)(ws + OFF_B2);
  float* Tt = (float*)(ws + OFF_T);
  float* Vt = (float*)(ws + OFF_V);
  float* Bi = (float*)(ws + OFF_BI);
  if (t < 33792) {                       // B1: (nt,kt,lane) -> 8 shorts
    int lane = t & 63, rest = t >> 6;
    int kt = rest % K1T, nt = rest / K1T;
    int col = nt * 16 + (lane & 15);
    int kb = kt * 32 + (lane >> 4) * 8;
    short8 v;
#pragma unroll
    for (int i = 0; i < 8; ++i) {
      int k = kb + i;
      v[i] = (k < 700) ? f2bf(W1g[k * 384 + col]) : (short)0;
    }
    *(short8*)(B1 + (size_t)t * 8) = v;
  } else if (t < 70656) {                // B2
    int t2 = t - 33792;
    int lane = t2 & 63, rest = t2 >> 6;
    int kt = rest % K2T, nt = rest / K2T;
    int col = nt * 16 + (lane & 15);
    int kb = kt * 32 + (lane >> 4) * 8;
    short8 v;
#pragma unroll
    for (int i = 0; i < 8; ++i) {
      int k = kb + i;
      v[i] = (k < 384) ? f2bf(W2g[k * 384 + col]) : f2bf(W2e[(k - 384) * 384 + col]);
    }
    *(short8*)(B2 + (size_t)t2 * 8) = v;
  } else if (t < 73728) {                // tables
    int r = t - 70656;
    int which = r / 384, c = r % 384;
    if (which < 6)       Tt[r] = W1e[which * 384 + c] + b1e[c];
    else if (which == 6) Vt[c] = W1e[6 * 384 + c];
    else                 Bi[c] = b2g[c] + b2e[c];
  }
}

__global__ void count_kernel(const float* __restrict__ isf1, const float* __restrict__ isf2,
                             char* __restrict__ ws) {
  int g = blockIdx.y;
  const float* isf = g ? isf2 : isf1;
  int i = blockIdx.x * 1024 + threadIdx.x;
  bool face = (i < NN) && (isf[i] > 0.5f);
  unsigned long long b = __ballot(face);
  __shared__ int wc[16];
  int lane = threadIdx.x & 63, wid = threadIdx.x >> 6;
  if (lane == 0) wc[wid] = __popcll(b);
  __syncthreads();
  if (threadIdx.x == 0) {
    int s = 0;
#pragma unroll
    for (int w = 0; w < 16; ++w) s += wc[w];
    ((int*)(ws + OFF_CNT))[g * NBLK + blockIdx.x] = s;
  }
}

__global__ void scan_kernel(char* __restrict__ ws) {
  int t = threadIdx.x;
  if (t < 2) {
    const int* cnt = (const int*)(ws + OFF_CNT) + t * NBLK;
    int* offs = (int*)(ws + OFF_OFFS) + t * NBLK;
    int* tot = (int*)(ws + OFF_TOT);
    int run = 0;
    for (int b = 0; b < NBLK; ++b) { offs[b] = run; run += cnt[b]; }
    tot[t] = run;
  }
}

__global__ void compact_kernel(const float* __restrict__ isf1, const float* __restrict__ isf2,
                               char* __restrict__ ws) {
  int g = blockIdx.y;
  const float* isf = g ? isf2 : isf1;
  const int* offs = (const int*)(ws + OFF_OFFS) + g * NBLK;
  int totF = ((const int*)(ws + OFF_TOT))[g];
  int* idx = (int*)(ws + OFF_IDX) + g * NN;
  int bx = blockIdx.x;
  int i = bx * 1024 + threadIdx.x;
  bool valid = i < NN;
  bool face = valid && (isf[i] > 0.5f);
  unsigned long long bf = __ballot(face);
  unsigned long long bv = __ballot(valid);
  int lane = threadIdx.x & 63, wid = threadIdx.x >> 6;
  __shared__ int wF[16], wV[16];
  if (lane == 0) { wF[wid] = __popcll(bf); wV[wid] = __popcll(bv); }
  __syncthreads();
  int baseF = 0, baseV = 0;
  for (int w = 0; w < wid; ++w) { baseF += wF[w]; baseV += wV[w]; }
  unsigned long long lmask = (1ull << lane) - 1ull;
  int pF = __popcll(bf & lmask);
  int pV = __popcll(bv & lmask);
  if (face) {
    idx[offs[bx] + baseF + pF] = i;
  } else if (valid) {
    int nfBefore = bx * 1024 - offs[bx];
    int nfIn = (baseV + pV) - (baseF + pF);
    idx[totF + nfBefore + nfIn] = i;
  }
}

// 64 gathered face rows/block, 256 thr = 4 waves, N-split-4: wave = 64r x 96c.
// ONE acc[4][6] array reused for both GEMMs (no accumulator live across phases
// beyond its own GEMM -> no spills; WRITE_SIZE is the canary).
// GEMM1: two serial k-panels [64][352 cols] bf16 (44 KB) in buf; h1 [64][768B]
// (48 KB) reuses buf; GEMM2 single 24-kt loop, entity branch inline (R5-style).
// 3 blocks/CU. Line-aligned epilogue.
__global__ __launch_bounds__(256, 3) void face_embed_kernel(
    const float* __restrict__ x1, const int* __restrict__ et1, const float* __restrict__ ar1,
    const float* __restrict__ x2, const int* __restrict__ et2, const float* __restrict__ ar2,
    const float* __restrict__ b1g, const char* __restrict__ ws,
    float* __restrict__ out) {
  const int g = blockIdx.y;
  const float* x = g ? x2 : x1;
  const int* et  = g ? et2 : et1;
  const float* ar = g ? ar2 : ar1;
  float* o = out + (size_t)g * NN * HD;
  const int* idx = (const int*)(ws + OFF_IDX) + g * NN;
  const int totF = ((const int*)(ws + OFF_TOT))[g];
  const int nFB = (totF + 63) >> 6;
  const int bx = blockIdx.x;
  const int tid = threadIdx.x;

  if (bx >= nFB) {                       // ---- zero path (64 non-face rows/block) ----
    int totN = NN - totF;
    int base = (bx - nFB) * 64;
    if (base >= totN) return;
    const int* idxN = idx + totF;
    f32x4 z = {0.f, 0.f, 0.f, 0.f};
#pragma unroll
    for (int it = 0; it < 24; ++it) {
      int c = tid + it * 256;            // 64 rows x 96 f32x4 chunks = 6144
      int r = c / 96, cc = c % 96;
      if (base + r < totN) {
        int node = idxN[base + r];
        *(f32x4*)(o + (size_t)node * HD + cc * 4) = z;
      }
    }
    return;
  }

  // ---- GEMM path ----
  __shared__ char buf[49152];            // panel [64][704B]=45056 / h1 [64][768B]=49152
  __shared__ int sN[64];

  const bf16x8* B1 = (const bf16x8*)(ws + OFF_B1);
  const bf16x8* B2 = (const bf16x8*)(ws + OFF_B2);
  const float* Tg  = (const float*)(ws + OFF_T);
  const float* Vg  = (const float*)(ws + OFF_V);
  const float* Big = (const float*)(ws + OFF_BI);

  const int row0 = bx * 64;
  if (tid < 64) sN[tid] = (row0 + tid < totF) ? idx[row0 + tid] : -1;
  __syncthreads();

  const int wid = tid >> 6, lane = tid & 63;
  const int lr = lane & 15, gq = lane >> 4;

  float b1c[6], b2c[6];
#pragma unroll
  for (int n = 0; n < 6; ++n) {
    int col = (wid * 6 + n) * 16 + lr;
    b1c[n] = b1g[col];
    b2c[n] = Big[col];
  }
  // entity params for the 4 A-row-frags of this lane (rows mf*16+lr)
  int nde[4]; float nda[4];
#pragma unroll
  for (int mf = 0; mf < 4; ++mf) {
    int node = sN[mf * 16 + lr];
    if (node >= 0) { nde[mf] = et[node]; nda[mf] = ar[node]; }
    else           { nde[mf] = 0;        nda[mf] = 0.f; }
  }

  // ---- panel staging: 64 rows x 88 f32x4 chunks (352 cols), 22 iters ----
  auto stage_panel = [&](int p) {
#pragma unroll 2
    for (int it = 0; it < 22; ++it) {
      int c = tid + it * 256;            // 5632 chunks
      int r = c / 88, cc = c % 88;
      int node = sN[r];
      int byte = (r * 704 + cc * 8) ^ ((r & 7) << 4);
      if (p == 1 && cc == 87) {          // global cols 700..703 -> zero
        *(unsigned long long*)(buf + byte) = 0ull;
      } else if (node >= 0) {
        f32x4 v = *(const f32x4*)(x + (size_t)node * 700 + p * 352 + cc * 4);
        svec4 pk;
#pragma unroll
        for (int i = 0; i < 4; ++i) pk[i] = f2bf(v[i]);
        *(svec4*)(buf + byte) = pk;
      }
    }
  };

  stage_panel(0);
  __syncthreads();

  f32x4 acc[4][6] = {};

  // ======== GEMM1 half 1: kt 0..10 ========
#pragma unroll
  for (int ktL = 0; ktL < 11; ++ktL) {
    Frag a[4];
#pragma unroll
    for (int mf = 0; mf < 4; ++mf) {
      int row = mf * 16 + lr;
      int byte = (row * 704 + ktL * 64 + gq * 16) ^ ((row & 7) << 4);
      a[mf].v = *(const bf16x8*)(buf + byte);
    }
#pragma unroll
    for (int n = 0; n < 6; ++n) {
      bf16x8 b = B1[((wid * 6 + n) * K1T + ktL) * 64 + lane];
#pragma unroll
      for (int mf = 0; mf < 4; ++mf)
        acc[mf][n] = __builtin_amdgcn_mfma_f32_16x16x32_bf16(a[mf].v, b, acc[mf][n], 0, 0, 0);
    }
  }
  __syncthreads();

  stage_panel(1);
  __syncthreads();

  // ======== GEMM1 half 2: kt 11..21 ========
#pragma unroll
  for (int ktL = 0; ktL < 11; ++ktL) {
    Frag a[4];
#pragma unroll
    for (int mf = 0; mf < 4; ++mf) {
      int row = mf * 16 + lr;
      int byte = (row * 704 + ktL * 64 + gq * 16) ^ ((row & 7) << 4);
      a[mf].v = *(const bf16x8*)(buf + byte);
    }
#pragma unroll
    for (int n = 0; n < 6; ++n) {
      bf16x8 b = B1[((wid * 6 + n) * K1T + 11 + ktL) * 64 + lane];
#pragma unroll
      for (int mf = 0; mf < 4; ++mf)
        acc[mf][n] = __builtin_amdgcn_mfma_f32_16x16x32_bf16(a[mf].v, b, acc[mf][n], 0, 0, 0);
    }
  }
  __syncthreads();

  // ======== h1 = elu(acc + b1) -> LDS [64][768B] swizzled; then acc reset ========
#pragma unroll
  for (int mf = 0; mf < 4; ++mf)
#pragma unroll
    for (int n = 0; n < 6; ++n) {
      int col = (wid * 6 + n) * 16 + lr;
#pragma unroll
      for (int r2 = 0; r2 < 4; ++r2) {
        int row = mf * 16 + 4 * gq + r2;
        float hv = elu(acc[mf][n][r2] + b1c[n]);
        int byte = (row * 768 + col * 2) ^ ((row & 15) << 4);
        *(short*)(buf + byte) = f2bf(hv);
      }
    }
  __syncthreads();

#pragma unroll
  for (int mf = 0; mf < 4; ++mf)
#pragma unroll
    for (int n = 0; n < 6; ++n)
      acc[mf][n] = (f32x4){0.f, 0.f, 0.f, 0.f};

  // ======== GEMM2: out = [h1|he] @ [W2g;W2e], single loop, he inline ========
  for (int kt = 0; kt < K2T; ++kt) {
    Frag a[4];
    if (kt < 12) {
#pragma unroll
      for (int mf = 0; mf < 4; ++mf) {
        int row = mf * 16 + lr;
        int byte = (row * 768 + (kt * 32 + gq * 8) * 2) ^ ((row & 15) << 4);
        a[mf].v = *(const bf16x8*)(buf + byte);
      }
    } else {
      int c0 = (kt - 12) * 32 + gq * 8;
#pragma unroll
      for (int mf = 0; mf < 4; ++mf) {
        const float* Tp = Tg + nde[mf] * 384 + c0;
        const float* Vp = Vg + c0;
#pragma unroll
        for (int i = 0; i < 8; ++i)
          a[mf].s[i] = f2bf(elu(Tp[i] + nda[mf] * Vp[i]));
      }
    }
#pragma unroll
    for (int n = 0; n < 6; ++n) {
      bf16x8 b = B2[((wid * 6 + n) * K2T + kt) * 64 + lane];
#pragma unroll
      for (int mf = 0; mf < 4; ++mf)
        acc[mf][n] = __builtin_amdgcn_mfma_f32_16x16x32_bf16(a[mf].v, b, acc[mf][n], 0, 0, 0);
    }
  }

  // ======== epilogue: +bias2, scatter store (wave region 384B line-aligned) ========
#pragma unroll
  for (int mf = 0; mf < 4; ++mf) {
#pragma unroll
    for (int r2 = 0; r2 < 4; ++r2) {
      int node = sN[mf * 16 + 4 * gq + r2];
      if (node >= 0) {
#pragma unroll
        for (int n = 0; n < 6; ++n) {
          int col = (wid * 6 + n) * 16 + lr;
          o[(size_t)node * HD + col] = acc[mf][n][r2] + b2c[n];
        }
      }
    }
  }
}

extern "C" void kernel_launch(void* const* d_in, const int* in_sizes, int n_in,
                              void* d_out, int out_size, void* d_ws, size_t ws_size,
                              hipStream_t stream) {
  (void)n_in; (void)out_size; (void)ws_size; (void)in_sizes;
  const float* x1  = (const float*)d_in[0];
  const float* is1 = (const float*)d_in[1];
  const int*   et1 = (const int*)d_in[2];
  const float* ar1 = (const float*)d_in[3];
  const float* x2  = (const float*)d_in[4];
  const float* is2 = (const float*)d_in[5];
  const int*   et2 = (const int*)d_in[6];
  const float* ar2 = (const float*)d_in[7];
  const float* W1g = (const float*)d_in[8];
  const float* b1g = (const float*)d_in[9];
  const float* W2g = (const float*)d_in[10];
  const float* b2g = (const float*)d_in[11];
  const float* W1e = (const float*)d_in[12];
  const float* b1e = (const float*)d_in[13];
  const float* W2e = (const float*)d_in[14];
  const float* b2e = (const float*)d_in[15];
  float* out = (float*)d_out;
  char* ws = (char*)d_ws;

  prep_kernel<<<dim3(288), dim3(256), 0, stream>>>(W1g, b1g, W2g, b2g, W1e, b1e, W2e, b2e, ws);
  count_kernel<<<dim3(NBLK, 2), dim3(1024), 0, stream>>>(is1, is2, ws);
  scan_kernel<<<dim3(1), dim3(64), 0, stream>>>(ws);
  compact_kernel<<<dim3(NBLK, 2), dim3(1024), 0, stream>>>(is1, is2, ws);

  dim3 grid(NN / 64 + 2, 2);
  face_embed_kernel<<<grid, dim3(256), 0, stream>>>(
      x1, et1, ar1, x2, et2, ar2, b1g, ws, out);
}